// Round 1
// baseline (1008.779 us; speedup 1.0000x reference)
//
#include <hip/hip_runtime.h>

#define LN_EPS 1e-5f

__device__ __forceinline__ float sigf(float x) { return 1.0f / (1.0f + __expf(-x)); }

// C[N,128] = epilogue(A[N,128] @ W[128,128] + bias)
// EPI 0: +bias (bias may be null)
// EPI 2: silu(.+bias) then rowwise LayerNorm * lng + lnb
template<int EPI>
__global__ __launch_bounds__(256, 1)
void gemm128(const float* __restrict__ A, const float* __restrict__ W,
             const float* __restrict__ bias, const float* __restrict__ lng,
             const float* __restrict__ lnb, float* __restrict__ C, int nrows)
{
    extern __shared__ float lds[];
    float* As = lds;             // [k][r] 128x128 (k-major, transposed tile)
    float* Ws = lds + 128 * 128; // [k][c] 128x128 (row-major)

    const int tid = threadIdx.x;
    const int r0 = blockIdx.x * 128;

    // stage W (coalesced, 16 float4 per thread)
    {
        const float4* W4 = (const float4*)W;
        float4* Ws4 = (float4*)Ws;
#pragma unroll
        for (int i = 0; i < 16; ++i) Ws4[tid + i * 256] = W4[tid + i * 256];
    }
    // stage A tile transposed: As[k][r] = A[r0+r][k]
    {
        const int r = tid & 127;
        const int kh = tid >> 7; // 0..1
        int gr = r0 + r; if (gr >= nrows) gr = nrows - 1;
        const float4* Arow = (const float4*)(A + (size_t)gr * 128);
#pragma unroll
        for (int q = 0; q < 16; ++q) {
            const int k4 = kh * 16 + q; // 0..31
            float4 v = Arow[k4];
            As[(k4 * 4 + 0) * 128 + r] = v.x;
            As[(k4 * 4 + 1) * 128 + r] = v.y;
            As[(k4 * 4 + 2) * 128 + r] = v.z;
            As[(k4 * 4 + 3) * 128 + r] = v.w;
        }
    }
    __syncthreads();

    const int tc = tid & 15;  // 16 thread-cols, cols tc*4..+3 and 64+tc*4..+3
    const int tr = tid >> 4;  // 16 thread-rows, rows tr*8..+7
    float acc[8][8];
#pragma unroll
    for (int i = 0; i < 8; ++i)
#pragma unroll
        for (int j = 0; j < 8; ++j) acc[i][j] = 0.f;

    const float* ap = As + tr * 8;
    const float* bp = Ws + tc * 4;
#pragma unroll 4
    for (int k = 0; k < 128; ++k) {
        float4 a0 = *(const float4*)(ap + k * 128);
        float4 a1 = *(const float4*)(ap + k * 128 + 4);
        float4 b0 = *(const float4*)(bp + k * 128);
        float4 b1 = *(const float4*)(bp + k * 128 + 64);
        float a[8] = {a0.x, a0.y, a0.z, a0.w, a1.x, a1.y, a1.z, a1.w};
        float b[8] = {b0.x, b0.y, b0.z, b0.w, b1.x, b1.y, b1.z, b1.w};
#pragma unroll
        for (int i = 0; i < 8; ++i)
#pragma unroll
            for (int j = 0; j < 8; ++j) acc[i][j] = fmaf(a[i], b[j], acc[i][j]);
    }

    int cj[8];
#pragma unroll
    for (int j = 0; j < 8; ++j) cj[j] = (j < 4) ? tc * 4 + j : 64 + tc * 4 + (j - 4);
    float bv[8];
#pragma unroll
    for (int j = 0; j < 8; ++j) bv[j] = bias ? bias[cj[j]] : 0.f;

    if (EPI == 0) {
#pragma unroll
        for (int i = 0; i < 8; ++i) {
            int gr = r0 + tr * 8 + i;
            if (gr < nrows) {
                float4 o0 = {acc[i][0] + bv[0], acc[i][1] + bv[1], acc[i][2] + bv[2], acc[i][3] + bv[3]};
                float4 o1 = {acc[i][4] + bv[4], acc[i][5] + bv[5], acc[i][6] + bv[6], acc[i][7] + bv[7]};
                *(float4*)(C + (size_t)gr * 128 + tc * 4) = o0;
                *(float4*)(C + (size_t)gr * 128 + 64 + tc * 4) = o1;
            }
        }
    } else {
        float gv[8], lbv[8];
#pragma unroll
        for (int j = 0; j < 8; ++j) { gv[j] = lng[cj[j]]; lbv[j] = lnb[cj[j]]; }
#pragma unroll
        for (int i = 0; i < 8; ++i) {
            float sum = 0.f, sq = 0.f;
#pragma unroll
            for (int j = 0; j < 8; ++j) {
                float v = acc[i][j] + bv[j];
                v = v * sigf(v); // silu
                acc[i][j] = v;
                sum += v; sq += v * v;
            }
            // reduce across the 16 lanes of this thread-row cluster
#pragma unroll
            for (int m = 1; m < 16; m <<= 1) { sum += __shfl_xor(sum, m); sq += __shfl_xor(sq, m); }
            float mean = sum * (1.f / 128.f);
            float var = sq * (1.f / 128.f) - mean * mean;
            float rstd = rsqrtf(var + LN_EPS);
            int gr = r0 + tr * 8 + i;
            if (gr < nrows) {
                float o[8];
#pragma unroll
                for (int j = 0; j < 8; ++j) o[j] = (acc[i][j] - mean) * rstd * gv[j] + lbv[j];
                *(float4*)(C + (size_t)gr * 128 + tc * 4) = {o[0], o[1], o[2], o[3]};
                *(float4*)(C + (size_t)gr * 128 + 64 + tc * 4) = {o[4], o[5], o[6], o[7]};
            }
        }
    }
}

// One wave per edge: att = sigmoid(dot(silu(xr[r]+xc[c]+ea*we), w2)+b2)*em;
// msg[r] += att * x_[c]  (atomic)
__global__ __launch_bounds__(256)
void edge_kernel(const float* __restrict__ xr, const float* __restrict__ xc,
                 const float* __restrict__ xm, const int* __restrict__ row,
                 const int* __restrict__ col, const float* __restrict__ ea,
                 const float* __restrict__ em, const float* __restrict__ we,
                 const float* __restrict__ w2, const float* __restrict__ b2p,
                 float* __restrict__ msg, int E)
{
    const int lane = threadIdx.x & 63;
    const int wid = (blockIdx.x * blockDim.x + threadIdx.x) >> 6;
    const int nw = (gridDim.x * blockDim.x) >> 6;
    const float2 wev = ((const float2*)we)[lane];
    const float2 w2v = ((const float2*)w2)[lane];
    const float b2 = *b2p;

    for (int e = wid; e < E; e += nw) {
        const int r = row[e], c = col[e];
        const float eav = ea[e], emv = em[e];
        float2 a = ((const float2*)xr)[(size_t)r * 64 + lane];
        float2 b = ((const float2*)xc)[(size_t)c * 64 + lane];
        float tx = a.x + b.x + eav * wev.x;
        float ty = a.y + b.y + eav * wev.y;
        float sx = tx * sigf(tx);
        float sy = ty * sigf(ty);
        float p = sx * w2v.x + sy * w2v.y;
#pragma unroll
        for (int m = 32; m; m >>= 1) p += __shfl_xor(p, m);
        const float att = sigf(p + b2) * emv;
        float2 v = ((const float2*)xm)[(size_t)c * 64 + lane];
        atomicAdd(&msg[(size_t)r * 128 + lane * 2], att * v.x);
        atomicAdd(&msg[(size_t)r * 128 + lane * 2 + 1], att * v.y);
    }
}

// out = LN(x + m2) * g + b, one wave per row
__global__ __launch_bounds__(256)
void final_ln(const float* __restrict__ x, const float* __restrict__ m2,
              const float* __restrict__ g, const float* __restrict__ b,
              float* __restrict__ out, int nrows)
{
    const int lane = threadIdx.x & 63;
    const int wid = (blockIdx.x * blockDim.x + threadIdx.x) >> 6;
    if (wid >= nrows) return;
    float2 a = ((const float2*)x)[(size_t)wid * 64 + lane];
    float2 c = ((const float2*)m2)[(size_t)wid * 64 + lane];
    float vx = a.x + c.x, vy = a.y + c.y;
    float sum = vx + vy, sq = vx * vx + vy * vy;
#pragma unroll
    for (int m = 32; m; m >>= 1) { sum += __shfl_xor(sum, m); sq += __shfl_xor(sq, m); }
    float mean = sum * (1.f / 128.f);
    float var = sq * (1.f / 128.f) - mean * mean;
    float rstd = rsqrtf(var + LN_EPS);
    float2 gg = ((const float2*)g)[lane];
    float2 bb = ((const float2*)b)[lane];
    float2 o = {(vx - mean) * rstd * gg.x + bb.x, (vy - mean) * rstd * gg.y + bb.y};
    ((float2*)out)[(size_t)wid * 64 + lane] = o;
}

extern "C" void kernel_launch(void* const* d_in, const int* in_sizes, int n_in,
                              void* d_out, int out_size, void* d_ws, size_t ws_size,
                              hipStream_t stream)
{
    const float* h        = (const float*)d_in[0];
    const float* edge_attr= (const float*)d_in[1];
    const int*   row      = (const int*)d_in[2];
    const int*   col      = (const int*)d_in[3];
    // d_in[4] = node_mask (unused by reference)
    const float* edge_mask= (const float*)d_in[5];
    const float* lin_w    = (const float*)d_in[6];
    const float* lin_b    = (const float*)d_in[7];
    const float* msg_w1   = (const float*)d_in[8];
    const float* msg_b1   = (const float*)d_in[9];
    const float* msg_ln_g = (const float*)d_in[10];
    const float* msg_ln_b = (const float*)d_in[11];
    const float* msg_w2   = (const float*)d_in[12];
    const float* msg_b2   = (const float*)d_in[13];
    const float* att_w1   = (const float*)d_in[14]; // [257,128]
    const float* att_b1   = (const float*)d_in[15];
    const float* att_w2   = (const float*)d_in[16]; // [128]
    const float* att_b2   = (const float*)d_in[17]; // [1]
    const float* out_w1   = (const float*)d_in[18];
    const float* out_b1   = (const float*)d_in[19];
    const float* out_ln_g = (const float*)d_in[20];
    const float* out_ln_b = (const float*)d_in[21];
    const float* out_w2   = (const float*)d_in[22];
    const float* out_b2   = (const float*)d_in[23];
    const float* ln_g     = (const float*)d_in[24];
    const float* ln_b     = (const float*)d_in[25];

    const int N = in_sizes[0] / 128;
    const int E = in_sizes[2];
    const size_t NF = (size_t)N * 128;

    float* ws = (float*)d_ws;
    float* x   = ws;            // B0
    float* x_  = ws + NF;       // B1: msg-net output; later out-net hidden
    float* xr  = ws + 2 * NF;   // B2: msg hidden (h1n); later xr; later m2
    float* xc  = ws + 3 * NF;   // B3
    float* msg = ws + 4 * NF;   // B4

    const int gblocks = (N + 127) / 128;
    const size_t LDS = 2 * 128 * 128 * sizeof(float); // 128 KiB

    // x = h @ lin_w + lin_b
    gemm128<0><<<gblocks, 256, LDS, stream>>>(h, lin_w, lin_b, nullptr, nullptr, x, N);
    // h1n = LN(silu(x @ msg_w1 + msg_b1))   (into B2, temp)
    gemm128<2><<<gblocks, 256, LDS, stream>>>(x, msg_w1, msg_b1, msg_ln_g, msg_ln_b, xr, N);
    // x_ = h1n @ msg_w2 + msg_b2
    gemm128<0><<<gblocks, 256, LDS, stream>>>(xr, msg_w2, msg_b2, nullptr, nullptr, x_, N);
    // xr = x @ att_w1[:128] + att_b1   (b1 folded here)
    gemm128<0><<<gblocks, 256, LDS, stream>>>(x, att_w1, att_b1, nullptr, nullptr, xr, N);
    // xc = x @ att_w1[128:256]
    gemm128<0><<<gblocks, 256, LDS, stream>>>(x, att_w1 + 128 * 128, nullptr, nullptr, nullptr, xc, N);

    hipMemsetAsync(msg, 0, NF * sizeof(float), stream);

    edge_kernel<<<2048, 256, 0, stream>>>(xr, xc, x_, row, col, edge_attr, edge_mask,
                                          att_w1 + 256 * 128, att_w2, att_b2, msg, E);

    // o1 = LN(silu(msg @ out_w1 + out_b1))  (into B1, x_ now dead)
    gemm128<2><<<gblocks, 256, LDS, stream>>>(msg, out_w1, out_b1, out_ln_g, out_ln_b, x_, N);
    // m2 = o1 @ out_w2 + out_b2  (into B2)
    gemm128<0><<<gblocks, 256, LDS, stream>>>(x_, out_w2, out_b2, nullptr, nullptr, xr, N);
    // out = LN(x + m2)
    final_ln<<<(N + 3) / 4, 256, 0, stream>>>(x, xr, ln_g, ln_b, (float*)d_out, N);
}

// Round 2
// 550.331 us; speedup vs baseline: 1.8330x; 1.8330x over previous
//
#include <hip/hip_runtime.h>

#define LN_EPS 1e-5f

__device__ __forceinline__ float sigf(float x) { return 1.0f / (1.0f + __expf(-x)); }

// C[N,128] = epilogue(A[N,128] @ W[128,128] + bias)
// EPI 0: +bias (bias may be null)
// EPI 2: silu(.+bias) then rowwise LayerNorm * lng + lnb
// EPI 3: (.+bias+res) then rowwise LayerNorm * lng + lnb   (residual + final LN)
template<int EPI>
__global__ __launch_bounds__(256, 1)
void gemm128(const float* __restrict__ A, const float* __restrict__ W,
             const float* __restrict__ bias, const float* __restrict__ lng,
             const float* __restrict__ lnb, const float* __restrict__ res,
             float* __restrict__ C, int nrows)
{
    extern __shared__ float lds[];
    float* As = lds;             // [k][r] 128x128 (k-major, transposed tile)
    float* Ws = lds + 128 * 128; // [k][c] 128x128 (row-major)

    const int tid = threadIdx.x;
    const int r0 = blockIdx.x * 128;

    // stage W (coalesced, 16 float4 per thread)
    {
        const float4* W4 = (const float4*)W;
        float4* Ws4 = (float4*)Ws;
#pragma unroll
        for (int i = 0; i < 16; ++i) Ws4[tid + i * 256] = W4[tid + i * 256];
    }
    // stage A tile transposed: As[k][r] = A[r0+r][k]
    {
        const int r = tid & 127;
        const int kh = tid >> 7; // 0..1
        int gr = r0 + r; if (gr >= nrows) gr = nrows - 1;
        const float4* Arow = (const float4*)(A + (size_t)gr * 128);
#pragma unroll
        for (int q = 0; q < 16; ++q) {
            const int k4 = kh * 16 + q; // 0..31
            float4 v = Arow[k4];
            As[(k4 * 4 + 0) * 128 + r] = v.x;
            As[(k4 * 4 + 1) * 128 + r] = v.y;
            As[(k4 * 4 + 2) * 128 + r] = v.z;
            As[(k4 * 4 + 3) * 128 + r] = v.w;
        }
    }
    __syncthreads();

    const int tc = tid & 15;  // 16 thread-cols, cols tc*4..+3 and 64+tc*4..+3
    const int tr = tid >> 4;  // 16 thread-rows, rows tr*8..+7
    float acc[8][8];
#pragma unroll
    for (int i = 0; i < 8; ++i)
#pragma unroll
        for (int j = 0; j < 8; ++j) acc[i][j] = 0.f;

    const float* ap = As + tr * 8;
    const float* bp = Ws + tc * 4;
#pragma unroll 4
    for (int k = 0; k < 128; ++k) {
        float4 a0 = *(const float4*)(ap + k * 128);
        float4 a1 = *(const float4*)(ap + k * 128 + 4);
        float4 b0 = *(const float4*)(bp + k * 128);
        float4 b1 = *(const float4*)(bp + k * 128 + 64);
        float a[8] = {a0.x, a0.y, a0.z, a0.w, a1.x, a1.y, a1.z, a1.w};
        float b[8] = {b0.x, b0.y, b0.z, b0.w, b1.x, b1.y, b1.z, b1.w};
#pragma unroll
        for (int i = 0; i < 8; ++i)
#pragma unroll
            for (int j = 0; j < 8; ++j) acc[i][j] = fmaf(a[i], b[j], acc[i][j]);
    }

    int cj[8];
#pragma unroll
    for (int j = 0; j < 8; ++j) cj[j] = (j < 4) ? tc * 4 + j : 64 + tc * 4 + (j - 4);
    float bv[8];
#pragma unroll
    for (int j = 0; j < 8; ++j) bv[j] = bias ? bias[cj[j]] : 0.f;

    if (EPI == 0) {
#pragma unroll
        for (int i = 0; i < 8; ++i) {
            int gr = r0 + tr * 8 + i;
            if (gr < nrows) {
                float4 o0 = {acc[i][0] + bv[0], acc[i][1] + bv[1], acc[i][2] + bv[2], acc[i][3] + bv[3]};
                float4 o1 = {acc[i][4] + bv[4], acc[i][5] + bv[5], acc[i][6] + bv[6], acc[i][7] + bv[7]};
                *(float4*)(C + (size_t)gr * 128 + tc * 4) = o0;
                *(float4*)(C + (size_t)gr * 128 + 64 + tc * 4) = o1;
            }
        }
    } else {
        float gv[8], lbv[8];
#pragma unroll
        for (int j = 0; j < 8; ++j) { gv[j] = lng[cj[j]]; lbv[j] = lnb[cj[j]]; }
#pragma unroll
        for (int i = 0; i < 8; ++i) {
            int gr = r0 + tr * 8 + i;
            int grc = gr < nrows ? gr : nrows - 1;
            float sum = 0.f, sq = 0.f;
#pragma unroll
            for (int j = 0; j < 8; ++j) {
                float v = acc[i][j] + bv[j];
                if (EPI == 2) {
                    v = v * sigf(v); // silu
                } else {
                    // residual add
                    v += res[(size_t)grc * 128 + cj[j]];
                }
                acc[i][j] = v;
                sum += v; sq += v * v;
            }
            // reduce across the 16 lanes of this thread-row cluster
#pragma unroll
            for (int m = 1; m < 16; m <<= 1) { sum += __shfl_xor(sum, m); sq += __shfl_xor(sq, m); }
            float mean = sum * (1.f / 128.f);
            float var = sq * (1.f / 128.f) - mean * mean;
            float rstd = rsqrtf(var + LN_EPS);
            if (gr < nrows) {
                float o[8];
#pragma unroll
                for (int j = 0; j < 8; ++j) o[j] = (acc[i][j] - mean) * rstd * gv[j] + lbv[j];
                *(float4*)(C + (size_t)gr * 128 + tc * 4) = {o[0], o[1], o[2], o[3]};
                *(float4*)(C + (size_t)gr * 128 + 64 + tc * 4) = {o[4], o[5], o[6], o[7]};
            }
        }
    }
}

// ---- counting sort of edges by row ----

__global__ __launch_bounds__(256)
void hist_k(const int* __restrict__ row, int* __restrict__ cnt, int E)
{
    for (int e = blockIdx.x * blockDim.x + threadIdx.x; e < E; e += gridDim.x * blockDim.x)
        atomicAdd(&cnt[row[e]], 1);
}

// single-block exclusive scan of cnt[0..n) -> off[0..n], cursor copy
__global__ __launch_bounds__(1024)
void scan_off(const int* __restrict__ cnt, int* __restrict__ off,
              int* __restrict__ cursor, int n)
{
    __shared__ int wsum[16];
    __shared__ int carry_s;
    const int tid = threadIdx.x, lane = tid & 63, wv = tid >> 6;
    if (tid == 0) carry_s = 0;
    __syncthreads();
    for (int base = 0; base < n; base += 1024) {
        const int i = base + tid;
        const int v = (i < n) ? cnt[i] : 0;
        int incl = v;
#pragma unroll
        for (int d = 1; d < 64; d <<= 1) { int t = __shfl_up(incl, d); if (lane >= d) incl += t; }
        if (lane == 63) wsum[wv] = incl;
        __syncthreads();
        if (tid == 0) {
            int run = 0;
            for (int w = 0; w < 16; ++w) { int t = wsum[w]; wsum[w] = run; run += t; }
        }
        __syncthreads();
        const int excl = carry_s + wsum[wv] + (incl - v);
        if (i < n) { off[i] = excl; cursor[i] = excl; }
        __syncthreads();
        if (tid == 1023) carry_s += wsum[15] + incl; // wave15 prefix + wave15 total
        __syncthreads();
    }
    if (tid == 0) off[n] = carry_s;
}

__global__ __launch_bounds__(256)
void scatter_k(const int* __restrict__ row, const int* __restrict__ col,
               const float* __restrict__ ea, const float* __restrict__ em,
               int* __restrict__ cursor, int* __restrict__ colS,
               float* __restrict__ eaS, float* __restrict__ emS, int E)
{
    for (int e = blockIdx.x * blockDim.x + threadIdx.x; e < E; e += gridDim.x * blockDim.x) {
        const int r = row[e];
        const int pos = atomicAdd(&cursor[r], 1);
        colS[pos] = col[e];
        eaS[pos] = ea[e];
        emS[pos] = em[e];
    }
}

// one wave per destination row: msg[r] = sum_e att(e) * x_[col(e)]
__global__ __launch_bounds__(256)
void row_accum(const float* __restrict__ xr, const float* __restrict__ xc,
               const float* __restrict__ xm, const int* __restrict__ off,
               const int* __restrict__ colS, const float* __restrict__ eaS,
               const float* __restrict__ emS, const float* __restrict__ we,
               const float* __restrict__ w2, const float* __restrict__ b2p,
               float* __restrict__ msg, int N)
{
    const int lane = threadIdx.x & 63;
    const int wid = (blockIdx.x * blockDim.x + threadIdx.x) >> 6;
    if (wid >= N) return;
    const float2 wev = ((const float2*)we)[lane];
    const float2 w2v = ((const float2*)w2)[lane];
    const float b2 = *b2p;
    const float2 a = ((const float2*)xr)[(size_t)wid * 64 + lane];
    int j = off[wid];
    const int jend = off[wid + 1];
    float accx = 0.f, accy = 0.f;

    for (; j + 2 <= jend; j += 2) {
        const int c0 = colS[j], c1 = colS[j + 1];
        const float ea0 = eaS[j], ea1 = eaS[j + 1];
        const float em0 = emS[j], em1 = emS[j + 1];
        const float2 b0 = ((const float2*)xc)[(size_t)c0 * 64 + lane];
        const float2 b1 = ((const float2*)xc)[(size_t)c1 * 64 + lane];
        const float2 v0 = ((const float2*)xm)[(size_t)c0 * 64 + lane];
        const float2 v1 = ((const float2*)xm)[(size_t)c1 * 64 + lane];
        const float t0x = a.x + b0.x + ea0 * wev.x, t0y = a.y + b0.y + ea0 * wev.y;
        const float t1x = a.x + b1.x + ea1 * wev.x, t1y = a.y + b1.y + ea1 * wev.y;
        float p0 = t0x * sigf(t0x) * w2v.x + t0y * sigf(t0y) * w2v.y;
        float p1 = t1x * sigf(t1x) * w2v.x + t1y * sigf(t1y) * w2v.y;
#pragma unroll
        for (int m = 32; m; m >>= 1) { p0 += __shfl_xor(p0, m); p1 += __shfl_xor(p1, m); }
        const float att0 = sigf(p0 + b2) * em0;
        const float att1 = sigf(p1 + b2) * em1;
        accx += att0 * v0.x + att1 * v1.x;
        accy += att0 * v0.y + att1 * v1.y;
    }
    if (j < jend) {
        const int c0 = colS[j];
        const float ea0 = eaS[j], em0 = emS[j];
        const float2 b0 = ((const float2*)xc)[(size_t)c0 * 64 + lane];
        const float2 v0 = ((const float2*)xm)[(size_t)c0 * 64 + lane];
        const float t0x = a.x + b0.x + ea0 * wev.x, t0y = a.y + b0.y + ea0 * wev.y;
        float p0 = t0x * sigf(t0x) * w2v.x + t0y * sigf(t0y) * w2v.y;
#pragma unroll
        for (int m = 32; m; m >>= 1) p0 += __shfl_xor(p0, m);
        const float att0 = sigf(p0 + b2) * em0;
        accx += att0 * v0.x;
        accy += att0 * v0.y;
    }
    ((float2*)msg)[(size_t)wid * 64 + lane] = {accx, accy};
}

extern "C" void kernel_launch(void* const* d_in, const int* in_sizes, int n_in,
                              void* d_out, int out_size, void* d_ws, size_t ws_size,
                              hipStream_t stream)
{
    const float* h        = (const float*)d_in[0];
    const float* edge_attr= (const float*)d_in[1];
    const int*   row      = (const int*)d_in[2];
    const int*   col      = (const int*)d_in[3];
    // d_in[4] = node_mask (unused by reference)
    const float* edge_mask= (const float*)d_in[5];
    const float* lin_w    = (const float*)d_in[6];
    const float* lin_b    = (const float*)d_in[7];
    const float* msg_w1   = (const float*)d_in[8];
    const float* msg_b1   = (const float*)d_in[9];
    const float* msg_ln_g = (const float*)d_in[10];
    const float* msg_ln_b = (const float*)d_in[11];
    const float* msg_w2   = (const float*)d_in[12];
    const float* msg_b2   = (const float*)d_in[13];
    const float* att_w1   = (const float*)d_in[14]; // [257,128]
    const float* att_b1   = (const float*)d_in[15];
    const float* att_w2   = (const float*)d_in[16]; // [128]
    const float* att_b2   = (const float*)d_in[17]; // [1]
    const float* out_w1   = (const float*)d_in[18];
    const float* out_b1   = (const float*)d_in[19];
    const float* out_ln_g = (const float*)d_in[20];
    const float* out_ln_b = (const float*)d_in[21];
    const float* out_w2   = (const float*)d_in[22];
    const float* out_b2   = (const float*)d_in[23];
    const float* ln_g     = (const float*)d_in[24];
    const float* ln_b     = (const float*)d_in[25];

    const int N = in_sizes[0] / 128;
    const int E = in_sizes[2];
    const size_t NF = (size_t)N * 128;

    float* ws = (float*)d_ws;
    float* x   = ws;            // B0
    float* x_  = ws + NF;       // B1: msg-net output; later out-net hidden
    float* xr  = ws + 2 * NF;   // B2: msg hidden (temp); later xr; later dead
    float* xc  = ws + 3 * NF;   // B3
    float* msg = ws + 4 * NF;   // B4
    // sort scratch after the 5 node buffers
    int*   cnt    = (int*)(ws + 5 * NF);
    int*   off    = cnt + N;            // N+1 entries
    int*   cursor = off + N + 8;
    int*   colS   = cursor + N + 8;
    float* eaS    = (float*)(colS + E);
    float* emS    = eaS + E;

    const int gblocks = (N + 127) / 128;
    const size_t LDS = 2 * 128 * 128 * sizeof(float); // 128 KiB

    // ---- edge counting sort (independent of GEMMs) ----
    hipMemsetAsync(cnt, 0, (size_t)N * sizeof(int), stream);
    hist_k<<<1024, 256, 0, stream>>>(row, cnt, E);
    scan_off<<<1, 1024, 0, stream>>>(cnt, off, cursor, N);
    scatter_k<<<1024, 256, 0, stream>>>(row, col, edge_attr, edge_mask,
                                        cursor, colS, eaS, emS, E);

    // ---- node GEMMs ----
    // x = h @ lin_w + lin_b
    gemm128<0><<<gblocks, 256, LDS, stream>>>(h, lin_w, lin_b, nullptr, nullptr, nullptr, x, N);
    // h1n = LN(silu(x @ msg_w1 + msg_b1))   (into B2, temp)
    gemm128<2><<<gblocks, 256, LDS, stream>>>(x, msg_w1, msg_b1, msg_ln_g, msg_ln_b, nullptr, xr, N);
    // x_ = h1n @ msg_w2 + msg_b2
    gemm128<0><<<gblocks, 256, LDS, stream>>>(xr, msg_w2, msg_b2, nullptr, nullptr, nullptr, x_, N);
    // xr = x @ att_w1[:128] + att_b1   (b1 folded here)
    gemm128<0><<<gblocks, 256, LDS, stream>>>(x, att_w1, att_b1, nullptr, nullptr, nullptr, xr, N);
    // xc = x @ att_w1[128:256]
    gemm128<0><<<gblocks, 256, LDS, stream>>>(x, att_w1 + 128 * 128, nullptr, nullptr, nullptr, nullptr, xc, N);

    // ---- per-row edge accumulation (no atomics) ----
    row_accum<<<(N + 3) / 4, 256, 0, stream>>>(xr, xc, x_, off, colS, eaS, emS,
                                               att_w1 + 256 * 128, att_w2, att_b2, msg, N);

    // ---- out net + residual + final LN ----
    // o1 = LN(silu(msg @ out_w1 + out_b1))  (into B1)
    gemm128<2><<<gblocks, 256, LDS, stream>>>(msg, out_w1, out_b1, out_ln_g, out_ln_b, nullptr, x_, N);
    // out = LN(x + o1 @ out_w2 + out_b2) * ln_g + ln_b  (fused residual + final LN)
    gemm128<3><<<gblocks, 256, LDS, stream>>>(x_, out_w2, out_b2, ln_g, ln_b, x, (float*)d_out, N);
}

// Round 3
// 378.562 us; speedup vs baseline: 2.6648x; 1.4537x over previous
//
#include <hip/hip_runtime.h>

#define LN_EPS 1e-5f

typedef __attribute__((ext_vector_type(8))) short short8;
typedef __attribute__((ext_vector_type(4))) float f32x4;

__device__ __forceinline__ float sigf(float x) { return 1.0f / (1.0f + __expf(-x)); }

__device__ __forceinline__ unsigned short f2bf(float f) {
    unsigned u = __float_as_uint(f);
    return (unsigned short)((u + 0x7fffu + ((u >> 16) & 1u)) >> 16);
}
__device__ __forceinline__ unsigned f2bf2(float lo, float hi) {
    return (unsigned)f2bf(lo) | ((unsigned)f2bf(hi) << 16);
}

// ---- weight prep: f32 [128][128] row-major -> fragment-linear bf16 ----
// B-frag for mfma_f32_16x16x32_bf16: frag(fn=n>>4, fk=k>>5), lane=(n&15)+16*kb,
// kb=(k>>3)&3, j=k&7.  addr(ushorts) = slot*16384 + ((fn*4+fk)*64+lane)*8 + j
__global__ __launch_bounds__(256)
void prep_w(const float* __restrict__ lin_w, const float* __restrict__ msg_w1,
            const float* __restrict__ msg_w2, const float* __restrict__ att_w1,
            const float* __restrict__ out_w1, const float* __restrict__ out_w2,
            const float* __restrict__ att_b1, unsigned short* __restrict__ wp,
            float* __restrict__ bias256)
{
    const int idx = blockIdx.x * 256 + threadIdx.x;
    if (idx < 8 * 16384) {
        const int m = idx >> 14, r = idx & 16383;
        const int k = r >> 7, n = r & 127;
        const float* src; int slot; int fnBase = 0;
        switch (m) {
            case 0: src = lin_w;  slot = 0; break;
            case 1: src = msg_w1; slot = 1; break;
            case 2: src = msg_w2; slot = 2; break;
            case 3: src = att_w1; slot = 3; break;              // combined att, cols 0-127
            case 4: src = att_w1 + 128 * 128; slot = 3; fnBase = 8; break; // cols 128-255
            case 5: src = out_w1; slot = 5; break;
            default: src = out_w2; slot = 6; break;
        }
        const float v = src[k * 128 + n];
        const int fn = fnBase + (n >> 4);
        const int fk = k >> 5, kb = (k >> 3) & 3, j = k & 7;
        const size_t dst = (size_t)slot * 16384 + ((size_t)((fn * 4 + fk) * 64 + (n & 15) + 16 * kb)) * 8 + j;
        wp[dst] = f2bf(v);
    } else if (idx < 8 * 16384 + 256) {
        const int t = idx - 8 * 16384;
        bias256[t] = (t < 128) ? att_b1[t] : 0.f;
    }
}

// ---- bf16 MFMA GEMM: C[N, NFN*16] = epi(A[N,128] @ W + bias) ----
// BM=64 rows/block, 4 waves, wave w owns rows w*16..w*16+15 x all cols.
// EPI 0: +bias; EPI 2: silu(.+bias) then LN; EPI 3: (.+bias+res) then LN
template<int EPI, int NFN>
__global__ __launch_bounds__(256, (NFN == 8 ? 3 : 2))
void gemm_mfma(const float* __restrict__ A, const unsigned short* __restrict__ Wp,
               const float* __restrict__ bias, const float* __restrict__ lng,
               const float* __restrict__ lnb, const float* __restrict__ res,
               float* __restrict__ C, int nrows)
{
    extern __shared__ uint4 lds[];
    uint4* ldsA = lds;            // 1024 packets = 16 KiB (frag-linear bf16)
    uint4* ldsB = lds + 1024;     // NFN*256 packets

    const int tid = threadIdx.x;
    const int r0 = blockIdx.x * 64;

    // stage B (already fragment-linear): linear copy
    const uint4* Wp4 = (const uint4*)Wp;
#pragma unroll
    for (int i = 0; i < NFN; ++i) ldsB[tid + i * 256] = Wp4[tid + i * 256];

    // stage A: f32 -> bf16, fragment-linear. packet p: row=p&63, kp=p>>6 (8 k's)
#pragma unroll
    for (int i = 0; i < 4; ++i) {
        const int p = i * 256 + tid;
        const int row = p & 63, kp = p >> 6;
        int gr = r0 + row; if (gr >= nrows) gr = nrows - 1;
        const float* ap = A + (size_t)gr * 128 + kp * 8;
        const float4 f0 = *(const float4*)ap;
        const float4 f1 = *(const float4*)(ap + 4);
        uint4 pk;
        pk.x = f2bf2(f0.x, f0.y); pk.y = f2bf2(f0.z, f0.w);
        pk.z = f2bf2(f1.x, f1.y); pk.w = f2bf2(f1.z, f1.w);
        const int fr = row >> 4, fk = kp >> 2, kb = kp & 3;
        ldsA[(fr * 4 + fk) * 64 + (row & 15) + 16 * kb] = pk;
    }
    __syncthreads();

    const int w = tid >> 6, lane = tid & 63;
    const short8* pA = (const short8*)ldsA;
    const short8* pB = (const short8*)ldsB;

    f32x4 acc[NFN];
#pragma unroll
    for (int fn = 0; fn < NFN; ++fn) acc[fn] = (f32x4){0.f, 0.f, 0.f, 0.f};

#pragma unroll
    for (int fk = 0; fk < 4; ++fk) {
        const short8 a = pA[(w * 4 + fk) * 64 + lane];
#pragma unroll
        for (int fn = 0; fn < NFN; ++fn) {
            const short8 b = pB[(fn * 4 + fk) * 64 + lane];
            acc[fn] = __builtin_amdgcn_mfma_f32_16x16x32_bf16(a, b, acc[fn], 0, 0, 0);
        }
    }

    // epilogue. C/D frag: col = lane&15, row = (lane>>4)*4 + reg  [m89]
    const int cn = lane & 15, rq = lane >> 4;
    const int CS = NFN * 16;
    float bv[NFN];
#pragma unroll
    for (int fn = 0; fn < NFN; ++fn) bv[fn] = bias ? bias[fn * 16 + cn] : 0.f;

    if (EPI == 0) {
#pragma unroll
        for (int reg = 0; reg < 4; ++reg) {
            const int gr = r0 + w * 16 + rq * 4 + reg;
            if (gr < nrows) {
#pragma unroll
                for (int fn = 0; fn < NFN; ++fn)
                    C[(size_t)gr * CS + fn * 16 + cn] = acc[fn][reg] + bv[fn];
            }
        }
    } else {
        float gv[NFN], bbv[NFN];
#pragma unroll
        for (int fn = 0; fn < NFN; ++fn) { gv[fn] = lng[fn * 16 + cn]; bbv[fn] = lnb[fn * 16 + cn]; }
#pragma unroll
        for (int reg = 0; reg < 4; ++reg) {
            const int gr = r0 + w * 16 + rq * 4 + reg;
            const int grc = gr < nrows ? gr : nrows - 1;
            float val[NFN];
            float sum = 0.f, sq = 0.f;
#pragma unroll
            for (int fn = 0; fn < NFN; ++fn) {
                float v = acc[fn][reg] + bv[fn];
                if (EPI == 2) v = v * sigf(v);
                else          v += res[(size_t)grc * CS + fn * 16 + cn];
                val[fn] = v; sum += v; sq += v * v;
            }
#pragma unroll
            for (int m = 1; m < 16; m <<= 1) { sum += __shfl_xor(sum, m); sq += __shfl_xor(sq, m); }
            const float mean = sum * (1.f / 128.f);
            const float var = sq * (1.f / 128.f) - mean * mean;
            const float rstd = rsqrtf(var + LN_EPS);
            if (gr < nrows) {
#pragma unroll
                for (int fn = 0; fn < NFN; ++fn)
                    C[(size_t)gr * CS + fn * 16 + cn] = (val[fn] - mean) * rstd * gv[fn] + bbv[fn];
            }
        }
    }
}

// ---- counting sort of edges by row ----

__global__ __launch_bounds__(256)
void hist_k(const int* __restrict__ row, int* __restrict__ cnt, int E)
{
    for (int e = blockIdx.x * blockDim.x + threadIdx.x; e < E; e += gridDim.x * blockDim.x)
        atomicAdd(&cnt[row[e]], 1);
}

// single-block exclusive scan; cursor may alias cnt (read-before-write per index)
__global__ __launch_bounds__(1024)
void scan_off(const int* __restrict__ cnt, int* __restrict__ off,
              int* __restrict__ cursor, int n)
{
    __shared__ int wsum[16];
    __shared__ int carry_s;
    const int tid = threadIdx.x, lane = tid & 63, wv = tid >> 6;
    if (tid == 0) carry_s = 0;
    __syncthreads();
    for (int base = 0; base < n; base += 1024) {
        const int i = base + tid;
        const int v = (i < n) ? cnt[i] : 0;
        int incl = v;
#pragma unroll
        for (int d = 1; d < 64; d <<= 1) { int t = __shfl_up(incl, d); if (lane >= d) incl += t; }
        if (lane == 63) wsum[wv] = incl;
        __syncthreads();
        if (tid == 0) {
            int run = 0;
            for (int ww = 0; ww < 16; ++ww) { int t = wsum[ww]; wsum[ww] = run; run += t; }
        }
        __syncthreads();
        const int excl = carry_s + wsum[wv] + (incl - v);
        if (i < n) { off[i] = excl; cursor[i] = excl; }
        __syncthreads();
        if (tid == 1023) carry_s += wsum[15] + incl;
        __syncthreads();
    }
    if (tid == 0) off[n] = carry_s;
}

__global__ __launch_bounds__(256)
void scatter_k(const int* __restrict__ row, const int* __restrict__ col,
               const float* __restrict__ ea, const float* __restrict__ em,
               int* __restrict__ cursor, int* __restrict__ colS,
               float* __restrict__ eaS, float* __restrict__ emS, int E)
{
    for (int e = blockIdx.x * blockDim.x + threadIdx.x; e < E; e += gridDim.x * blockDim.x) {
        const int r = row[e];
        const int pos = atomicAdd(&cursor[r], 1);
        colS[pos] = col[e];
        eaS[pos] = ea[e];
        emS[pos] = em[e];
    }
}

// one wave per destination row: msg[r] = sum_e att(e) * x_[col(e)]
// xrc is [N][256]: cols 0-127 = xr, cols 128-255 = xc
__global__ __launch_bounds__(256)
void row_accum(const float* __restrict__ xrc, const float* __restrict__ xm,
               const int* __restrict__ off, const int* __restrict__ colS,
               const float* __restrict__ eaS, const float* __restrict__ emS,
               const float* __restrict__ we, const float* __restrict__ w2,
               const float* __restrict__ b2p, float* __restrict__ msg, int N)
{
    const int lane = threadIdx.x & 63;
    const int wid = (blockIdx.x * blockDim.x + threadIdx.x) >> 6;
    if (wid >= N) return;
    const float2 wev = ((const float2*)we)[lane];
    const float2 w2v = ((const float2*)w2)[lane];
    const float b2 = *b2p;
    const float2 a = ((const float2*)(xrc + (size_t)wid * 256))[lane];
    int j = off[wid];
    const int jend = off[wid + 1];
    float accx = 0.f, accy = 0.f;

    for (; j + 2 <= jend; j += 2) {
        const int c0 = colS[j], c1 = colS[j + 1];
        const float ea0 = eaS[j], ea1 = eaS[j + 1];
        const float em0 = emS[j], em1 = emS[j + 1];
        const float2 b0 = ((const float2*)(xrc + (size_t)c0 * 256 + 128))[lane];
        const float2 b1 = ((const float2*)(xrc + (size_t)c1 * 256 + 128))[lane];
        const float2 v0 = ((const float2*)xm)[(size_t)c0 * 64 + lane];
        const float2 v1 = ((const float2*)xm)[(size_t)c1 * 64 + lane];
        const float t0x = a.x + b0.x + ea0 * wev.x, t0y = a.y + b0.y + ea0 * wev.y;
        const float t1x = a.x + b1.x + ea1 * wev.x, t1y = a.y + b1.y + ea1 * wev.y;
        float p0 = t0x * sigf(t0x) * w2v.x + t0y * sigf(t0y) * w2v.y;
        float p1 = t1x * sigf(t1x) * w2v.x + t1y * sigf(t1y) * w2v.y;
#pragma unroll
        for (int m = 32; m; m >>= 1) { p0 += __shfl_xor(p0, m); p1 += __shfl_xor(p1, m); }
        const float att0 = sigf(p0 + b2) * em0;
        const float att1 = sigf(p1 + b2) * em1;
        accx += att0 * v0.x + att1 * v1.x;
        accy += att0 * v0.y + att1 * v1.y;
    }
    if (j < jend) {
        const int c0 = colS[j];
        const float ea0 = eaS[j], em0 = emS[j];
        const float2 b0 = ((const float2*)(xrc + (size_t)c0 * 256 + 128))[lane];
        const float2 v0 = ((const float2*)xm)[(size_t)c0 * 64 + lane];
        const float t0x = a.x + b0.x + ea0 * wev.x, t0y = a.y + b0.y + ea0 * wev.y;
        float p0 = t0x * sigf(t0x) * w2v.x + t0y * sigf(t0y) * w2v.y;
#pragma unroll
        for (int m = 32; m; m >>= 1) p0 += __shfl_xor(p0, m);
        const float att0 = sigf(p0 + b2) * em0;
        accx += att0 * v0.x;
        accy += att0 * v0.y;
    }
    ((float2*)msg)[(size_t)wid * 64 + lane] = {accx, accy};
}

extern "C" void kernel_launch(void* const* d_in, const int* in_sizes, int n_in,
                              void* d_out, int out_size, void* d_ws, size_t ws_size,
                              hipStream_t stream)
{
    const float* h        = (const float*)d_in[0];
    const float* edge_attr= (const float*)d_in[1];
    const int*   row      = (const int*)d_in[2];
    const int*   col      = (const int*)d_in[3];
    const float* edge_mask= (const float*)d_in[5];
    const float* lin_w    = (const float*)d_in[6];
    const float* lin_b    = (const float*)d_in[7];
    const float* msg_w1   = (const float*)d_in[8];
    const float* msg_b1   = (const float*)d_in[9];
    const float* msg_ln_g = (const float*)d_in[10];
    const float* msg_ln_b = (const float*)d_in[11];
    const float* msg_w2   = (const float*)d_in[12];
    const float* msg_b2   = (const float*)d_in[13];
    const float* att_w1   = (const float*)d_in[14]; // [257,128]
    const float* att_b1   = (const float*)d_in[15];
    const float* att_w2   = (const float*)d_in[16];
    const float* att_b2   = (const float*)d_in[17];
    const float* out_w1   = (const float*)d_in[18];
    const float* out_b1   = (const float*)d_in[19];
    const float* out_ln_g = (const float*)d_in[20];
    const float* out_ln_b = (const float*)d_in[21];
    const float* out_w2   = (const float*)d_in[22];
    const float* out_b2   = (const float*)d_in[23];
    const float* ln_g     = (const float*)d_in[24];
    const float* ln_b     = (const float*)d_in[25];

    const int N = in_sizes[0] / 128;
    const int E = in_sizes[2];
    const size_t NF = (size_t)N * 128;

    float* ws = (float*)d_ws;
    float* x    = ws;            // B0: x (kept for residual)
    float* x_   = ws + NF;       // B1: msg-net output (xm); later out-net hidden
    float* xrc  = ws + 2 * NF;   // B2+B3: msg hidden temp, then [N][256] xr|xc
    float* msg  = ws + 4 * NF;   // B4
    int*   cnt    = (int*)(ws + 5 * NF);  // also reused as cursor
    int*   off    = cnt + N;              // N+1 (alloc N+8)
    int*   colS   = off + N + 8;
    float* eaS    = (float*)(colS + E);
    float* emS    = eaS + E;
    unsigned short* wp = (unsigned short*)(emS + E); // 8*16384 bf16 (frag-linear)
    float* bias256 = (float*)(wp + 8 * 16384);       // att bias, zero-padded

    const int gb = (N + 63) / 64;
    const size_t LDS8  = (1024 + 8 * 256) * sizeof(uint4);  // 48 KiB
    const size_t LDS16 = (1024 + 16 * 256) * sizeof(uint4); // 80 KiB

    // weight prep + edge counting sort (independent of GEMM chain)
    prep_w<<<513, 256, 0, stream>>>(lin_w, msg_w1, msg_w2, att_w1, out_w1, out_w2,
                                    att_b1, wp, bias256);
    hipMemsetAsync(cnt, 0, (size_t)N * sizeof(int), stream);
    hist_k<<<1024, 256, 0, stream>>>(row, cnt, E);
    scan_off<<<1, 1024, 0, stream>>>(cnt, off, cnt, N);
    scatter_k<<<1024, 256, 0, stream>>>(row, col, edge_attr, edge_mask,
                                        cnt, colS, eaS, emS, E);

    // x = h @ lin_w + lin_b
    gemm_mfma<0, 8><<<gb, 256, LDS8, stream>>>(h, wp, lin_b, nullptr, nullptr, nullptr, x, N);
    // h1n = LN(silu(x @ msg_w1 + msg_b1))  (temp in B2)
    gemm_mfma<2, 8><<<gb, 256, LDS8, stream>>>(x, wp + 16384, msg_b1, msg_ln_g, msg_ln_b, nullptr, xrc, N);
    // x_ = h1n @ msg_w2 + msg_b2
    gemm_mfma<0, 8><<<gb, 256, LDS8, stream>>>(xrc, wp + 2 * 16384, msg_b2, nullptr, nullptr, nullptr, x_, N);
    // xrc = x @ [att_w1[:128] | att_w1[128:256]] + [att_b1|0]   (overwrites h1n)
    gemm_mfma<0, 16><<<gb, 256, LDS16, stream>>>(x, wp + 3 * 16384, bias256, nullptr, nullptr, nullptr, xrc, N);

    // per-row edge accumulation (no atomics)
    row_accum<<<(N + 3) / 4, 256, 0, stream>>>(xrc, x_, off, colS, eaS, emS,
                                               att_w1 + 256 * 128, att_w2, att_b2, msg, N);

    // o1 = LN(silu(msg @ out_w1 + out_b1))  (into B1, x_ dead after row_accum)
    gemm_mfma<2, 8><<<gb, 256, LDS8, stream>>>(msg, wp + 5 * 16384, out_b1, out_ln_g, out_ln_b, nullptr, x_, N);
    // out = LN(x + o1 @ out_w2 + out_b2) * ln_g + ln_b
    gemm_mfma<3, 8><<<gb, 256, LDS8, stream>>>(x_, wp + 6 * 16384, out_b2, ln_g, ln_b, x, (float*)d_out, N);
}

// Round 4
// 354.170 us; speedup vs baseline: 2.8483x; 1.0689x over previous
//
#include <hip/hip_runtime.h>

#define LN_EPS 1e-5f

typedef __attribute__((ext_vector_type(8))) short short8;
typedef __attribute__((ext_vector_type(4))) float f32x4;

__device__ __forceinline__ float sigf(float x) { return 1.0f / (1.0f + __expf(-x)); }

__device__ __forceinline__ unsigned short f2bf(float f) {
    unsigned u = __float_as_uint(f);
    return (unsigned short)((u + 0x7fffu + ((u >> 16) & 1u)) >> 16);
}
__device__ __forceinline__ unsigned f2bf2(float lo, float hi) {
    return (unsigned)f2bf(lo) | ((unsigned)f2bf(hi) << 16);
}
__device__ __forceinline__ void bf2f(unsigned u, float& lo, float& hi) {
    lo = __uint_as_float(u << 16);
    hi = __uint_as_float(u & 0xffff0000u);
}
__device__ __forceinline__ void bf8f(uint4 p, float* o) {
    bf2f(p.x, o[0], o[1]); bf2f(p.y, o[2], o[3]);
    bf2f(p.z, o[4], o[5]); bf2f(p.w, o[6], o[7]);
}

// ---- weight prep: f32 [128][128] row-major -> fragment-linear bf16 ----
__global__ __launch_bounds__(256)
void prep_w(const float* __restrict__ lin_w, const float* __restrict__ msg_w1,
            const float* __restrict__ msg_w2, const float* __restrict__ att_w1,
            const float* __restrict__ out_w1, const float* __restrict__ out_w2,
            const float* __restrict__ att_b1, unsigned short* __restrict__ wp,
            float* __restrict__ bias256)
{
    const int idx = blockIdx.x * 256 + threadIdx.x;
    if (idx < 8 * 16384) {
        const int m = idx >> 14, r = idx & 16383;
        const int k = r >> 7, n = r & 127;
        const float* src; int slot; int fnBase = 0;
        switch (m) {
            case 0: src = lin_w;  slot = 0; break;
            case 1: src = msg_w1; slot = 1; break;
            case 2: src = msg_w2; slot = 2; break;
            case 3: src = att_w1; slot = 3; break;
            case 4: src = att_w1 + 128 * 128; slot = 3; fnBase = 8; break;
            case 5: src = out_w1; slot = 5; break;
            default: src = out_w2; slot = 6; break;
        }
        const float v = src[k * 128 + n];
        const int fn = fnBase + (n >> 4);
        const int fk = k >> 5, kb = (k >> 3) & 3, j = k & 7;
        const size_t dst = (size_t)slot * 16384 + ((size_t)((fn * 4 + fk) * 64 + (n & 15) + 16 * kb)) * 8 + j;
        wp[dst] = f2bf(v);
    } else if (idx < 8 * 16384 + 256) {
        const int t = idx - 8 * 16384;
        bias256[t] = (t < 128) ? att_b1[t] : 0.f;
    }
}

// ---- bf16 MFMA GEMM: C[N, NFN*16] = epi(A[N,128] @ W + bias) ----
// ABF: A is bf16; OBF: C written as bf16
// EPI 0: +bias; EPI 2: silu(.+bias) then LN; EPI 3: (.+bias+res) then LN
template<int EPI, int NFN, int ABF, int OBF>
__global__ __launch_bounds__(256, (NFN == 8 ? 3 : 2))
void gemm_mfma(const void* __restrict__ Av, const unsigned short* __restrict__ Wp,
               const float* __restrict__ bias, const float* __restrict__ lng,
               const float* __restrict__ lnb, const float* __restrict__ res,
               void* __restrict__ Cv, int nrows)
{
    extern __shared__ uint4 lds[];
    uint4* ldsA = lds;            // 1024 packets (frag-linear bf16)
    uint4* ldsB = lds + 1024;     // NFN*256 packets

    const int tid = threadIdx.x;
    const int r0 = blockIdx.x * 64;

    const uint4* Wp4 = (const uint4*)Wp;
#pragma unroll
    for (int i = 0; i < NFN; ++i) ldsB[tid + i * 256] = Wp4[tid + i * 256];

#pragma unroll
    for (int i = 0; i < 4; ++i) {
        const int p = i * 256 + tid;
        const int row = p & 63, kp = p >> 6;
        int gr = r0 + row; if (gr >= nrows) gr = nrows - 1;
        uint4 pk;
        if (ABF) {
            pk = *(const uint4*)((const unsigned short*)Av + (size_t)gr * 128 + kp * 8);
        } else {
            const float* ap = (const float*)Av + (size_t)gr * 128 + kp * 8;
            const float4 f0 = *(const float4*)ap;
            const float4 f1 = *(const float4*)(ap + 4);
            pk.x = f2bf2(f0.x, f0.y); pk.y = f2bf2(f0.z, f0.w);
            pk.z = f2bf2(f1.x, f1.y); pk.w = f2bf2(f1.z, f1.w);
        }
        const int fr = row >> 4, fk = kp >> 2, kb = kp & 3;
        ldsA[(fr * 4 + fk) * 64 + (row & 15) + 16 * kb] = pk;
    }
    __syncthreads();

    const int w = tid >> 6, lane = tid & 63;
    const short8* pA = (const short8*)ldsA;
    const short8* pB = (const short8*)ldsB;

    f32x4 acc[NFN];
#pragma unroll
    for (int fn = 0; fn < NFN; ++fn) acc[fn] = (f32x4){0.f, 0.f, 0.f, 0.f};

#pragma unroll
    for (int fk = 0; fk < 4; ++fk) {
        const short8 a = pA[(w * 4 + fk) * 64 + lane];
#pragma unroll
        for (int fn = 0; fn < NFN; ++fn) {
            const short8 b = pB[(fn * 4 + fk) * 64 + lane];
            acc[fn] = __builtin_amdgcn_mfma_f32_16x16x32_bf16(a, b, acc[fn], 0, 0, 0);
        }
    }

    const int cn = lane & 15, rq = lane >> 4;
    const int CS = NFN * 16;
    float* Cf = (float*)Cv;
    unsigned short* Ch = (unsigned short*)Cv;
    float bv[NFN];
#pragma unroll
    for (int fn = 0; fn < NFN; ++fn) bv[fn] = bias ? bias[fn * 16 + cn] : 0.f;

    if (EPI == 0) {
#pragma unroll
        for (int reg = 0; reg < 4; ++reg) {
            const int gr = r0 + w * 16 + rq * 4 + reg;
            if (gr < nrows) {
#pragma unroll
                for (int fn = 0; fn < NFN; ++fn) {
                    const float v = acc[fn][reg] + bv[fn];
                    if (OBF) Ch[(size_t)gr * CS + fn * 16 + cn] = f2bf(v);
                    else     Cf[(size_t)gr * CS + fn * 16 + cn] = v;
                }
            }
        }
    } else {
        float gv[NFN], bbv[NFN];
#pragma unroll
        for (int fn = 0; fn < NFN; ++fn) { gv[fn] = lng[fn * 16 + cn]; bbv[fn] = lnb[fn * 16 + cn]; }
#pragma unroll
        for (int reg = 0; reg < 4; ++reg) {
            const int gr = r0 + w * 16 + rq * 4 + reg;
            const int grc = gr < nrows ? gr : nrows - 1;
            float val[NFN];
            float sum = 0.f, sq = 0.f;
#pragma unroll
            for (int fn = 0; fn < NFN; ++fn) {
                float v = acc[fn][reg] + bv[fn];
                if (EPI == 2) v = v * sigf(v);
                else          v += res[(size_t)grc * CS + fn * 16 + cn];
                val[fn] = v; sum += v; sq += v * v;
            }
#pragma unroll
            for (int m = 1; m < 16; m <<= 1) { sum += __shfl_xor(sum, m); sq += __shfl_xor(sq, m); }
            const float mean = sum * (1.f / 128.f);
            const float var = sq * (1.f / 128.f) - mean * mean;
            const float rstd = rsqrtf(var + LN_EPS);
            if (gr < nrows) {
#pragma unroll
                for (int fn = 0; fn < NFN; ++fn) {
                    const float v = (val[fn] - mean) * rstd * gv[fn] + bbv[fn];
                    if (OBF) Ch[(size_t)gr * CS + fn * 16 + cn] = f2bf(v);
                    else     Cf[(size_t)gr * CS + fn * 16 + cn] = v;
                }
            }
        }
    }
}

// ---- counting sort of edges by row ----

__global__ __launch_bounds__(256)
void hist_k(const int* __restrict__ row, int* __restrict__ cnt, int E)
{
    for (int e = blockIdx.x * blockDim.x + threadIdx.x; e < E; e += gridDim.x * blockDim.x)
        atomicAdd(&cnt[row[e]], 1);
}

__global__ __launch_bounds__(1024)
void scan_off(const int* __restrict__ cnt, int* __restrict__ off,
              int* __restrict__ cursor, int n)
{
    __shared__ int wsum[16];
    __shared__ int carry_s;
    const int tid = threadIdx.x, lane = tid & 63, wv = tid >> 6;
    if (tid == 0) carry_s = 0;
    __syncthreads();
    for (int base = 0; base < n; base += 1024) {
        const int i = base + tid;
        const int v = (i < n) ? cnt[i] : 0;
        int incl = v;
#pragma unroll
        for (int d = 1; d < 64; d <<= 1) { int t = __shfl_up(incl, d); if (lane >= d) incl += t; }
        if (lane == 63) wsum[wv] = incl;
        __syncthreads();
        if (tid == 0) {
            int run = 0;
            for (int ww = 0; ww < 16; ++ww) { int t = wsum[ww]; wsum[ww] = run; run += t; }
        }
        __syncthreads();
        const int excl = carry_s + wsum[wv] + (incl - v);
        if (i < n) { off[i] = excl; cursor[i] = excl; }
        __syncthreads();
        if (tid == 1023) carry_s += wsum[15] + incl;
        __syncthreads();
    }
    if (tid == 0) off[n] = carry_s;
}

__global__ __launch_bounds__(256)
void scatter_k(const int* __restrict__ row, const int* __restrict__ col,
               const float* __restrict__ ea, const float* __restrict__ em,
               int* __restrict__ cursor, int* __restrict__ colS,
               float2* __restrict__ eamS, int E)
{
    for (int e = blockIdx.x * blockDim.x + threadIdx.x; e < E; e += gridDim.x * blockDim.x) {
        const int r = row[e];
        const int pos = atomicAdd(&cursor[r], 1);
        colS[pos] = col[e];
        eamS[pos] = make_float2(ea[e], em[e]);
    }
}

// ---- per-row edge accumulation ----
// wave = 4 groups x 16 lanes; group g handles edge j0+g; lane l holds comps l*8..+8
// xrcH bf16 [N][256] (xr|xc), xmH bf16 [N][128]
__global__ __launch_bounds__(256)
void row_accum(const unsigned short* __restrict__ xrcH,
               const unsigned short* __restrict__ xmH,
               const int* __restrict__ off, const int* __restrict__ colS,
               const float2* __restrict__ eamS, const float* __restrict__ we_,
               const float* __restrict__ w2_, const float* __restrict__ b2p,
               float* __restrict__ msg, int N)
{
    const int lane = threadIdx.x & 63;
    const int wid = (blockIdx.x * blockDim.x + threadIdx.x) >> 6;
    if (wid >= N) return;
    const int g = lane >> 4, l = lane & 15;

    float xr[8], we[8], w2[8];
    bf8f(((const uint4*)(xrcH + (size_t)wid * 256))[l], xr);
    {
        float4 a = ((const float4*)we_)[l * 2], b = ((const float4*)we_)[l * 2 + 1];
        we[0] = a.x; we[1] = a.y; we[2] = a.z; we[3] = a.w;
        we[4] = b.x; we[5] = b.y; we[6] = b.z; we[7] = b.w;
        float4 c = ((const float4*)w2_)[l * 2], d = ((const float4*)w2_)[l * 2 + 1];
        w2[0] = c.x; w2[1] = c.y; w2[2] = c.z; w2[3] = c.w;
        w2[4] = d.x; w2[5] = d.y; w2[6] = d.z; w2[7] = d.w;
    }
    const float b2 = *b2p;
    int j0 = off[wid];
    const int jend = off[wid + 1];
    float acc[8] = {0.f, 0.f, 0.f, 0.f, 0.f, 0.f, 0.f, 0.f};

    for (; j0 < jend; j0 += 4) {
        const int je = j0 + g;
        const bool valid = je < jend;
        const int jc = valid ? je : jend - 1;
        const int c = colS[jc];
        const float2 eam = eamS[jc];
        const float emv = valid ? eam.y : 0.f;
        float xc[8], xm[8];
        bf8f(((const uint4*)(xrcH + (size_t)c * 256 + 128))[l], xc);
        bf8f(((const uint4*)(xmH + (size_t)c * 128))[l], xm);
        float p = 0.f;
#pragma unroll
        for (int i = 0; i < 8; ++i) {
            const float t = xr[i] + xc[i] + eam.x * we[i];
            p += t * sigf(t) * w2[i];
        }
#pragma unroll
        for (int m = 1; m < 16; m <<= 1) p += __shfl_xor(p, m);
        const float att = sigf(p + b2) * emv;
#pragma unroll
        for (int i = 0; i < 8; ++i) acc[i] = fmaf(att, xm[i], acc[i]);
    }

#pragma unroll
    for (int i = 0; i < 8; ++i) {
        acc[i] += __shfl_xor(acc[i], 16);
        acc[i] += __shfl_xor(acc[i], 32);
    }
    if (g == 0) {
        float* mrow = msg + (size_t)wid * 128 + l * 8;
        *(float4*)mrow = {acc[0], acc[1], acc[2], acc[3]};
        *(float4*)(mrow + 4) = {acc[4], acc[5], acc[6], acc[7]};
    }
}

extern "C" void kernel_launch(void* const* d_in, const int* in_sizes, int n_in,
                              void* d_out, int out_size, void* d_ws, size_t ws_size,
                              hipStream_t stream)
{
    const float* h        = (const float*)d_in[0];
    const float* edge_attr= (const float*)d_in[1];
    const int*   row      = (const int*)d_in[2];
    const int*   col      = (const int*)d_in[3];
    const float* edge_mask= (const float*)d_in[5];
    const float* lin_w    = (const float*)d_in[6];
    const float* lin_b    = (const float*)d_in[7];
    const float* msg_w1   = (const float*)d_in[8];
    const float* msg_b1   = (const float*)d_in[9];
    const float* msg_ln_g = (const float*)d_in[10];
    const float* msg_ln_b = (const float*)d_in[11];
    const float* msg_w2   = (const float*)d_in[12];
    const float* msg_b2   = (const float*)d_in[13];
    const float* att_w1   = (const float*)d_in[14];
    const float* att_b1   = (const float*)d_in[15];
    const float* att_w2   = (const float*)d_in[16];
    const float* att_b2   = (const float*)d_in[17];
    const float* out_w1   = (const float*)d_in[18];
    const float* out_b1   = (const float*)d_in[19];
    const float* out_ln_g = (const float*)d_in[20];
    const float* out_ln_b = (const float*)d_in[21];
    const float* out_w2   = (const float*)d_in[22];
    const float* out_b2   = (const float*)d_in[23];
    const float* ln_g     = (const float*)d_in[24];
    const float* ln_b     = (const float*)d_in[25];

    const int N = in_sizes[0] / 128;
    const int E = in_sizes[2];
    const size_t NF = (size_t)N * 128;

    float* x    = (float*)d_ws;                        // f32 [N][128]
    float* msg  = x + NF;                              // f32 [N][128]
    unsigned short* hb   = (unsigned short*)(msg + NF);// bf16 [N][128] h1n / o1
    unsigned short* xmH  = hb + NF;                    // bf16 [N][128]
    unsigned short* xrcH = xmH + NF;                   // bf16 [N][256]
    int*    cnt   = (int*)(xrcH + 2 * NF);
    int*    off   = cnt + N;                           // N+1 (alloc N+8)
    int*    colS  = off + N + 8;
    float2* eamS  = (float2*)(colS + E);
    unsigned short* wp = (unsigned short*)(eamS + E);
    float* bias256 = (float*)(wp + 8 * 16384);

    const int gb = (N + 63) / 64;
    const size_t LDS8  = (1024 + 8 * 256) * sizeof(uint4);  // 48 KiB
    const size_t LDS16 = (1024 + 16 * 256) * sizeof(uint4); // 80 KiB

    prep_w<<<513, 256, 0, stream>>>(lin_w, msg_w1, msg_w2, att_w1, out_w1, out_w2,
                                    att_b1, wp, bias256);
    hipMemsetAsync(cnt, 0, (size_t)N * sizeof(int), stream);
    hist_k<<<1024, 256, 0, stream>>>(row, cnt, E);
    scan_off<<<1, 1024, 0, stream>>>(cnt, off, cnt, N);
    scatter_k<<<1024, 256, 0, stream>>>(row, col, edge_attr, edge_mask,
                                        cnt, colS, eamS, E);

    // x = h @ lin_w + lin_b                                  (f32 -> f32)
    gemm_mfma<0, 8, 0, 0><<<gb, 256, LDS8, stream>>>(h, wp, lin_b, nullptr, nullptr, nullptr, x, N);
    // h1n = LN(silu(x @ msg_w1 + msg_b1))                    (f32 -> bf16)
    gemm_mfma<2, 8, 0, 1><<<gb, 256, LDS8, stream>>>(x, wp + 16384, msg_b1, msg_ln_g, msg_ln_b, nullptr, hb, N);
    // xm = h1n @ msg_w2 + msg_b2                             (bf16 -> bf16)
    gemm_mfma<0, 8, 1, 1><<<gb, 256, LDS8, stream>>>(hb, wp + 2 * 16384, msg_b2, nullptr, nullptr, nullptr, xmH, N);
    // xrc = x @ [att_w1[:128] | att_w1[128:256]] + [b1|0]    (f32 -> bf16, 256 cols)
    gemm_mfma<0, 16, 0, 1><<<gb, 256, LDS16, stream>>>(x, wp + 3 * 16384, bias256, nullptr, nullptr, nullptr, xrcH, N);

    row_accum<<<(N + 3) / 4, 256, 0, stream>>>(xrcH, xmH, off, colS, eamS,
                                               att_w1 + 256 * 128, att_w2, att_b2, msg, N);

    // o1 = LN(silu(msg @ out_w1 + out_b1))                   (f32 -> bf16)
    gemm_mfma<2, 8, 0, 1><<<gb, 256, LDS8, stream>>>(msg, wp + 5 * 16384, out_b1, out_ln_g, out_ln_b, nullptr, hb, N);
    // out = LN(x + o1 @ out_w2 + out_b2) * ln_g + ln_b       (bf16 -> f32, residual)
    gemm_mfma<3, 8, 1, 0><<<gb, 256, LDS8, stream>>>(hb, wp + 6 * 16384, out_b2, ln_g, ln_b, x, (float*)d_out, N);
}

// Round 5
// 310.584 us; speedup vs baseline: 3.2480x; 1.1403x over previous
//
#include <hip/hip_runtime.h>

#define LN_EPS 1e-5f

typedef __attribute__((ext_vector_type(8))) short short8;
typedef __attribute__((ext_vector_type(4))) float f32x4;
typedef unsigned short ushort_t;

__device__ __forceinline__ float sigf(float x) { return 1.0f / (1.0f + __expf(-x)); }

__device__ __forceinline__ unsigned short f2bf(float f) {
    unsigned u = __float_as_uint(f);
    return (unsigned short)((u + 0x7fffu + ((u >> 16) & 1u)) >> 16);
}
__device__ __forceinline__ unsigned f2bf2(float lo, float hi) {
    return (unsigned)f2bf(lo) | ((unsigned)f2bf(hi) << 16);
}
__device__ __forceinline__ void bf2f(unsigned u, float& lo, float& hi) {
    lo = __uint_as_float(u << 16);
    hi = __uint_as_float(u & 0xffff0000u);
}
__device__ __forceinline__ void bf8f(uint4 p, float* o) {
    bf2f(p.x, o[0], o[1]); bf2f(p.y, o[2], o[3]);
    bf2f(p.z, o[4], o[5]); bf2f(p.w, o[6], o[7]);
}

// ---- weight prep: f32 [128][128] row-major -> fragment-linear bf16 ----
__global__ __launch_bounds__(256)
void prep_w(const float* __restrict__ lin_w, const float* __restrict__ msg_w1,
            const float* __restrict__ msg_w2, const float* __restrict__ att_w1,
            const float* __restrict__ out_w1, const float* __restrict__ out_w2,
            const float* __restrict__ att_b1, unsigned short* __restrict__ wp,
            float* __restrict__ bias256)
{
    const int idx = blockIdx.x * 256 + threadIdx.x;
    if (idx < 8 * 16384) {
        const int m = idx >> 14, r = idx & 16383;
        const int k = r >> 7, n = r & 127;
        const float* src; int slot; int fnBase = 0;
        switch (m) {
            case 0: src = lin_w;  slot = 0; break;
            case 1: src = msg_w1; slot = 1; break;
            case 2: src = msg_w2; slot = 2; break;
            case 3: src = att_w1; slot = 3; break;
            case 4: src = att_w1 + 128 * 128; slot = 3; fnBase = 8; break;
            case 5: src = out_w1; slot = 5; break;
            default: src = out_w2; slot = 6; break;
        }
        const float v = src[k * 128 + n];
        const int fn = fnBase + (n >> 4);
        const int fk = k >> 5, kb = (k >> 3) & 3, j = k & 7;
        const size_t dst = (size_t)slot * 16384 + ((size_t)((fn * 4 + fk) * 64 + (n & 15) + 16 * kb)) * 8 + j;
        wp[dst] = f2bf(v);
    } else if (idx < 8 * 16384 + 256) {
        const int t = idx - 8 * 16384;
        bias256[t] = (t < 128) ? att_b1[t] : 0.f;
    }
}

// ---- bf16 MFMA GEMM: epi(A[N,128] @ W + bias) with flexible destinations ----
// ABF: A bf16.  OBF: 0 = f32 C1; 1 = bf16 C1; 2 = f32 C1 + bf16 copy C2.
// SPLIT (NFN=16 only): fn<8 -> bf16 C1/ld1, fn>=8 -> bf16 C2/ld2 (fn rebased).
// EPI 0: +bias; EPI 2: silu(.+bias) then LN; EPI 3: (.+bias+res) then LN
template<int EPI, int NFN, int ABF, int OBF, int SPLIT>
__global__ __launch_bounds__(256, (NFN == 8 ? 3 : 2))
void gemm_mfma(const void* __restrict__ Av, const unsigned short* __restrict__ Wp,
               const float* __restrict__ bias, const float* __restrict__ lng,
               const float* __restrict__ lnb, const float* __restrict__ res,
               void* __restrict__ C1v, int ld1, void* __restrict__ C2v, int ld2,
               int nrows)
{
    extern __shared__ uint4 lds[];
    uint4* ldsA = lds;            // 1024 packets (frag-linear bf16)
    uint4* ldsB = lds + 1024;     // NFN*256 packets

    const int tid = threadIdx.x;
    const int r0 = blockIdx.x * 64;

    const uint4* Wp4 = (const uint4*)Wp;
#pragma unroll
    for (int i = 0; i < NFN; ++i) ldsB[tid + i * 256] = Wp4[tid + i * 256];

#pragma unroll
    for (int i = 0; i < 4; ++i) {
        const int p = i * 256 + tid;
        const int row = p & 63, kp = p >> 6;
        int gr = r0 + row; if (gr >= nrows) gr = nrows - 1;
        uint4 pk;
        if (ABF) {
            pk = *(const uint4*)((const unsigned short*)Av + (size_t)gr * 128 + kp * 8);
        } else {
            const float* ap = (const float*)Av + (size_t)gr * 128 + kp * 8;
            const float4 f0 = *(const float4*)ap;
            const float4 f1 = *(const float4*)(ap + 4);
            pk.x = f2bf2(f0.x, f0.y); pk.y = f2bf2(f0.z, f0.w);
            pk.z = f2bf2(f1.x, f1.y); pk.w = f2bf2(f1.z, f1.w);
        }
        const int fr = row >> 4, fk = kp >> 2, kb = kp & 3;
        ldsA[(fr * 4 + fk) * 64 + (row & 15) + 16 * kb] = pk;
    }
    __syncthreads();

    const int w = tid >> 6, lane = tid & 63;
    const short8* pA = (const short8*)ldsA;
    const short8* pB = (const short8*)ldsB;

    f32x4 acc[NFN];
#pragma unroll
    for (int fn = 0; fn < NFN; ++fn) acc[fn] = (f32x4){0.f, 0.f, 0.f, 0.f};

#pragma unroll
    for (int fk = 0; fk < 4; ++fk) {
        const short8 a = pA[(w * 4 + fk) * 64 + lane];
#pragma unroll
        for (int fn = 0; fn < NFN; ++fn) {
            const short8 b = pB[(fn * 4 + fk) * 64 + lane];
            acc[fn] = __builtin_amdgcn_mfma_f32_16x16x32_bf16(a, b, acc[fn], 0, 0, 0);
        }
    }

    const int cn = lane & 15, rq = lane >> 4;
    float* C1f = (float*)C1v;
    unsigned short* C1h = (unsigned short*)C1v;
    unsigned short* C2h = (unsigned short*)C2v;
    float bv[NFN];
#pragma unroll
    for (int fn = 0; fn < NFN; ++fn) bv[fn] = bias ? bias[fn * 16 + cn] : 0.f;

    if (EPI == 0) {
#pragma unroll
        for (int reg = 0; reg < 4; ++reg) {
            const int gr = r0 + w * 16 + rq * 4 + reg;
            if (gr < nrows) {
#pragma unroll
                for (int fn = 0; fn < NFN; ++fn) {
                    const float v = acc[fn][reg] + bv[fn];
                    if (SPLIT) {
                        if (fn < 8) C1h[(size_t)gr * ld1 + fn * 16 + cn] = f2bf(v);
                        else        C2h[(size_t)gr * ld2 + (fn - 8) * 16 + cn] = f2bf(v);
                    } else if (OBF == 1) {
                        C1h[(size_t)gr * ld1 + fn * 16 + cn] = f2bf(v);
                    } else if (OBF == 2) {
                        C1f[(size_t)gr * ld1 + fn * 16 + cn] = v;
                        C2h[(size_t)gr * ld2 + fn * 16 + cn] = f2bf(v);
                    } else {
                        C1f[(size_t)gr * ld1 + fn * 16 + cn] = v;
                    }
                }
            }
        }
    } else {
        float gv[NFN], bbv[NFN];
#pragma unroll
        for (int fn = 0; fn < NFN; ++fn) { gv[fn] = lng[fn * 16 + cn]; bbv[fn] = lnb[fn * 16 + cn]; }
#pragma unroll
        for (int reg = 0; reg < 4; ++reg) {
            const int gr = r0 + w * 16 + rq * 4 + reg;
            const int grc = gr < nrows ? gr : nrows - 1;
            float val[NFN];
            float sum = 0.f, sq = 0.f;
#pragma unroll
            for (int fn = 0; fn < NFN; ++fn) {
                float v = acc[fn][reg] + bv[fn];
                if (EPI == 2) v = v * sigf(v);
                else          v += res[(size_t)grc * ld1 + fn * 16 + cn];
                val[fn] = v; sum += v; sq += v * v;
            }
#pragma unroll
            for (int m = 1; m < 16; m <<= 1) { sum += __shfl_xor(sum, m); sq += __shfl_xor(sq, m); }
            const float mean = sum * (1.f / 128.f);
            const float var = sq * (1.f / 128.f) - mean * mean;
            const float rstd = rsqrtf(var + LN_EPS);
            if (gr < nrows) {
#pragma unroll
                for (int fn = 0; fn < NFN; ++fn) {
                    const float v = (val[fn] - mean) * rstd * gv[fn] + bbv[fn];
                    if (OBF == 1) C1h[(size_t)gr * ld1 + fn * 16 + cn] = f2bf(v);
                    else          C1f[(size_t)gr * ld1 + fn * 16 + cn] = v;
                }
            }
        }
    }
}

// ---- counting sort of edges by row ----

__global__ __launch_bounds__(256)
void hist_k(const int* __restrict__ row, int* __restrict__ cnt, int E)
{
    for (int e = blockIdx.x * blockDim.x + threadIdx.x; e < E; e += gridDim.x * blockDim.x)
        atomicAdd(&cnt[row[e]], 1);
}

// multi-block scan: (a) per-block exclusive scan + block totals
__global__ __launch_bounds__(1024)
void scan_a(const int* __restrict__ cnt, int* __restrict__ off,
            int* __restrict__ btot, int n)
{
    __shared__ int wsum[16];
    const int tid = threadIdx.x, lane = tid & 63, wv = tid >> 6;
    const int i = blockIdx.x * 1024 + tid;
    const int v = (i < n) ? cnt[i] : 0;
    int incl = v;
#pragma unroll
    for (int d = 1; d < 64; d <<= 1) { int t = __shfl_up(incl, d); if (lane >= d) incl += t; }
    if (lane == 63) wsum[wv] = incl;
    __syncthreads();
    if (tid == 0) {
        int run = 0;
        for (int ww = 0; ww < 16; ++ww) { int t = wsum[ww]; wsum[ww] = run; run += t; }
    }
    __syncthreads();
    if (i < n) off[i] = wsum[wv] + incl - v;
    if (tid == 1023) btot[blockIdx.x] = wsum[15] + incl;
}

// (b) single-wave scan of block totals (nb <= 64); also writes off[n] = E
__global__ __launch_bounds__(64)
void scan_b(int* __restrict__ btot, int* __restrict__ bexc,
            int* __restrict__ off, int n, int nb, int E)
{
    const int t = threadIdx.x;
    const int v = (t < nb) ? btot[t] : 0;
    int incl = v;
#pragma unroll
    for (int d = 1; d < 64; d <<= 1) { int u = __shfl_up(incl, d); if (t >= d) incl += u; }
    if (t < nb) bexc[t] = incl - v;
    if (t == 0) off[n] = E;
}

// (c) add block offsets, produce cursor
__global__ __launch_bounds__(1024)
void scan_c(int* __restrict__ off, const int* __restrict__ bexc,
            int* __restrict__ cursor, int n)
{
    const int i = blockIdx.x * 1024 + threadIdx.x;
    if (i < n) {
        const int o = off[i] + bexc[blockIdx.x];
        off[i] = o;
        cursor[i] = o;
    }
}

__global__ __launch_bounds__(256)
void scatter_k(const int* __restrict__ row, const int* __restrict__ col,
               const float* __restrict__ ea, const float* __restrict__ em,
               int* __restrict__ cursor, int* __restrict__ colS,
               float2* __restrict__ eamS, int E)
{
    for (int e = blockIdx.x * blockDim.x + threadIdx.x; e < E; e += gridDim.x * blockDim.x) {
        const int r = row[e];
        const int pos = atomicAdd(&cursor[r], 1);
        colS[pos] = col[e];
        eamS[pos] = make_float2(ea[e], em[e]);
    }
}

// ---- per-row edge accumulation ----
// wave = 4 groups x 16 lanes; group g handles one edge; lane l holds comps l*8..+8
// xrH bf16 [N][128]; xcmH bf16 [N][256]: shorts 0-127 = xc, 128-255 = xm
__global__ __launch_bounds__(256)
void row_accum(const unsigned short* __restrict__ xrH,
               const unsigned short* __restrict__ xcmH,
               const int* __restrict__ off, const int* __restrict__ colS,
               const float2* __restrict__ eamS, const float* __restrict__ we_,
               const float* __restrict__ w2_, const float* __restrict__ b2p,
               float* __restrict__ msg, int N)
{
    const int lane = threadIdx.x & 63;
    const int wid = (blockIdx.x * blockDim.x + threadIdx.x) >> 6;
    if (wid >= N) return;
    const int g = lane >> 4, l = lane & 15;
    const uint4* xcm4 = (const uint4*)xcmH;

    float xr[8], we[8], w2[8];
    bf8f(((const uint4*)(xrH + (size_t)wid * 128))[l], xr);
    {
        float4 a = ((const float4*)we_)[l * 2], b = ((const float4*)we_)[l * 2 + 1];
        we[0] = a.x; we[1] = a.y; we[2] = a.z; we[3] = a.w;
        we[4] = b.x; we[5] = b.y; we[6] = b.z; we[7] = b.w;
        float4 c = ((const float4*)w2_)[l * 2], d = ((const float4*)w2_)[l * 2 + 1];
        w2[0] = c.x; w2[1] = c.y; w2[2] = c.z; w2[3] = c.w;
        w2[4] = d.x; w2[5] = d.y; w2[6] = d.z; w2[7] = d.w;
    }
    const float b2 = *b2p;
    int j0 = off[wid];
    const int jend = off[wid + 1];
    float acc[8] = {0.f, 0.f, 0.f, 0.f, 0.f, 0.f, 0.f, 0.f};

    // main: 8 edges per iteration (two groups-of-4), 4 gathers in flight
    for (; j0 + 8 <= jend; j0 += 8) {
        const int jA = j0 + g, jB = j0 + 4 + g;
        const int cA = colS[jA], cB = colS[jB];
        const float2 eA = eamS[jA], eB = eamS[jB];
        const size_t bA = (size_t)cA * 32 + l, bB = (size_t)cB * 32 + l;
        const uint4 pcA = xcm4[bA], pmA = xcm4[bA + 16];
        const uint4 pcB = xcm4[bB], pmB = xcm4[bB + 16];
        float xcA[8], xmA[8], xcB[8], xmB[8];
        bf8f(pcA, xcA); bf8f(pmA, xmA);
        bf8f(pcB, xcB); bf8f(pmB, xmB);
        float pA = 0.f, pB = 0.f;
#pragma unroll
        for (int i = 0; i < 8; ++i) {
            const float tA = xr[i] + xcA[i] + eA.x * we[i];
            const float tB = xr[i] + xcB[i] + eB.x * we[i];
            pA += tA * sigf(tA) * w2[i];
            pB += tB * sigf(tB) * w2[i];
        }
#pragma unroll
        for (int m = 1; m < 16; m <<= 1) { pA += __shfl_xor(pA, m); pB += __shfl_xor(pB, m); }
        const float attA = sigf(pA + b2) * eA.y;
        const float attB = sigf(pB + b2) * eB.y;
#pragma unroll
        for (int i = 0; i < 8; ++i) acc[i] = fmaf(attB, xmB[i], fmaf(attA, xmA[i], acc[i]));
    }

    // tail: up to 7 edges, guarded
    for (; j0 < jend; j0 += 4) {
        const int je = j0 + g;
        const bool valid = je < jend;
        const int jc = valid ? je : jend - 1;
        const int c = colS[jc];
        const float2 eam = eamS[jc];
        const float emv = valid ? eam.y : 0.f;
        const size_t b = (size_t)c * 32 + l;
        const uint4 pc = xcm4[b], pm = xcm4[b + 16];
        float xc[8], xm[8];
        bf8f(pc, xc); bf8f(pm, xm);
        float p = 0.f;
#pragma unroll
        for (int i = 0; i < 8; ++i) {
            const float t = xr[i] + xc[i] + eam.x * we[i];
            p += t * sigf(t) * w2[i];
        }
#pragma unroll
        for (int m = 1; m < 16; m <<= 1) p += __shfl_xor(p, m);
        const float att = sigf(p + b2) * emv;
#pragma unroll
        for (int i = 0; i < 8; ++i) acc[i] = fmaf(att, xm[i], acc[i]);
    }

#pragma unroll
    for (int i = 0; i < 8; ++i) {
        acc[i] += __shfl_xor(acc[i], 16);
        acc[i] += __shfl_xor(acc[i], 32);
    }
    if (g == 0) {
        float* mrow = msg + (size_t)wid * 128 + l * 8;
        *(float4*)mrow = {acc[0], acc[1], acc[2], acc[3]};
        *(float4*)(mrow + 4) = {acc[4], acc[5], acc[6], acc[7]};
    }
}

extern "C" void kernel_launch(void* const* d_in, const int* in_sizes, int n_in,
                              void* d_out, int out_size, void* d_ws, size_t ws_size,
                              hipStream_t stream)
{
    const float* h        = (const float*)d_in[0];
    const float* edge_attr= (const float*)d_in[1];
    const int*   row      = (const int*)d_in[2];
    const int*   col      = (const int*)d_in[3];
    const float* edge_mask= (const float*)d_in[5];
    const float* lin_w    = (const float*)d_in[6];
    const float* lin_b    = (const float*)d_in[7];
    const float* msg_w1   = (const float*)d_in[8];
    const float* msg_b1   = (const float*)d_in[9];
    const float* msg_ln_g = (const float*)d_in[10];
    const float* msg_ln_b = (const float*)d_in[11];
    const float* msg_w2   = (const float*)d_in[12];
    const float* msg_b2   = (const float*)d_in[13];
    const float* att_w1   = (const float*)d_in[14];
    const float* att_b1   = (const float*)d_in[15];
    const float* att_w2   = (const float*)d_in[16];
    const float* att_b2   = (const float*)d_in[17];
    const float* out_w1   = (const float*)d_in[18];
    const float* out_b1   = (const float*)d_in[19];
    const float* out_ln_g = (const float*)d_in[20];
    const float* out_ln_b = (const float*)d_in[21];
    const float* out_w2   = (const float*)d_in[22];
    const float* out_b2   = (const float*)d_in[23];
    const float* ln_g     = (const float*)d_in[24];
    const float* ln_b     = (const float*)d_in[25];

    const int N = in_sizes[0] / 128;
    const int E = in_sizes[2];
    const size_t NF = (size_t)N * 128;

    float* x    = (float*)d_ws;                         // f32 [N][128]
    float* msg  = x + NF;                               // f32 [N][128]
    unsigned short* hb   = (unsigned short*)(msg + NF); // bf16 [N][128] h1n / o1
    unsigned short* xbH  = hb + NF;                     // bf16 [N][128] copy of x
    unsigned short* xrH  = xbH + NF;                    // bf16 [N][128]
    unsigned short* xcmH = xrH + NF;                    // bf16 [N][256] xc|xm
    int*    cnt   = (int*)(xcmH + 2 * NF);              // N (reused as cursor)
    int*    off   = cnt + N;                            // N+1 (alloc N+8)
    int*    btot  = off + N + 8;                        // 64
    int*    bexc  = btot + 64;                          // 64
    int*    colS  = bexc + 64;                          // E
    float2* eamS  = (float2*)(colS + E);                // E
    unsigned short* wp = (unsigned short*)(eamS + E);   // 8*16384 bf16
    float* bias256 = (float*)(wp + 8 * 16384);

    const int gb = (N + 63) / 64;
    const int nb = (N + 1023) / 1024;
    const size_t LDS8  = (1024 + 8 * 256) * sizeof(uint4);  // 48 KiB
    const size_t LDS16 = (1024 + 16 * 256) * sizeof(uint4); // 80 KiB

    prep_w<<<513, 256, 0, stream>>>(lin_w, msg_w1, msg_w2, att_w1, out_w1, out_w2,
                                    att_b1, wp, bias256);
    hipMemsetAsync(cnt, 0, (size_t)N * sizeof(int), stream);
    hist_k<<<1024, 256, 0, stream>>>(row, cnt, E);
    scan_a<<<nb, 1024, 0, stream>>>(cnt, off, btot, N);
    scan_b<<<1, 64, 0, stream>>>(btot, bexc, off, N, nb, E);
    scan_c<<<nb, 1024, 0, stream>>>(off, bexc, cnt, N);
    scatter_k<<<1024, 256, 0, stream>>>(row, col, edge_attr, edge_mask,
                                        cnt, colS, eamS, E);

    // x = h @ lin_w + lin_b                    (f32 out + bf16 copy)
    gemm_mfma<0, 8, 0, 2, 0><<<gb, 256, LDS8, stream>>>(h, wp, lin_b, nullptr, nullptr, nullptr,
                                                        x, 128, xbH, 128, N);
    // h1n = LN(silu(x @ msg_w1 + msg_b1))      (bf16 in/out)
    gemm_mfma<2, 8, 1, 1, 0><<<gb, 256, LDS8, stream>>>(xbH, wp + 16384, msg_b1, msg_ln_g, msg_ln_b, nullptr,
                                                        hb, 128, nullptr, 0, N);
    // xm = h1n @ msg_w2 + msg_b2               (bf16 -> xcm cols 128-255)
    gemm_mfma<0, 8, 1, 1, 0><<<gb, 256, LDS8, stream>>>(hb, wp + 2 * 16384, msg_b2, nullptr, nullptr, nullptr,
                                                        xcmH + 128, 256, nullptr, 0, N);
    // xr|xc = x @ att_w1[0:256] + [b1|0]       (split: xr -> xrH, xc -> xcm cols 0-127)
    gemm_mfma<0, 16, 1, 1, 1><<<gb, 256, LDS16, stream>>>(xbH, wp + 3 * 16384, bias256, nullptr, nullptr, nullptr,
                                                          xrH, 128, xcmH, 256, N);

    row_accum<<<(N + 3) / 4, 256, 0, stream>>>(xrH, xcmH, off, colS, eamS,
                                               att_w1 + 256 * 128, att_w2, att_b2, msg, N);

    // o1 = LN(silu(msg @ out_w1 + out_b1))
    gemm_mfma<2, 8, 0, 1, 0><<<gb, 256, LDS8, stream>>>(msg, wp + 5 * 16384, out_b1, out_ln_g, out_ln_b, nullptr,
                                                        hb, 128, nullptr, 0, N);
    // out = LN(x + o1 @ out_w2 + out_b2) * ln_g + ln_b
    gemm_mfma<3, 8, 1, 0, 0><<<gb, 256, LDS8, stream>>>(hb, wp + 6 * 16384, out_b2, ln_g, ln_b, x,
                                                        (float*)d_out, 128, nullptr, 0, N);
}